// Round 1
// baseline (1132.044 us; speedup 1.0000x reference)
//
#include <hip/hip_runtime.h>
#include <math.h>

#define N_NODES 50000
#define N_EDGES 800000
#define D_IN 64
#define D_HID 128

// ============================ CSR build ============================

__global__ void count_kernel(const int* __restrict__ dst, int* __restrict__ deg, int E) {
    int i = blockIdx.x * blockDim.x + threadIdx.x;
    if (i < E) atomicAdd(&deg[dst[i]], 1);
}

// Single-block exclusive scan over deg[n] -> off[n+1]
__global__ void scan_kernel(const int* __restrict__ deg, int* __restrict__ off, int n) {
    __shared__ int sums[1024];
    const int t = threadIdx.x;
    const int per = (n + 1023) / 1024;  // 49 for n=50000
    int start = t * per, end = min(start + per, n);
    int s = 0;
    for (int i = start; i < end; i++) s += deg[i];
    sums[t] = s;
    __syncthreads();
    for (int o = 1; o < 1024; o <<= 1) {
        int v = 0;
        if (t >= o) v = sums[t - o];
        __syncthreads();
        sums[t] += v;
        __syncthreads();
    }
    int run = (t == 0) ? 0 : sums[t - 1];
    for (int i = start; i < end; i++) { off[i] = run; run += deg[i]; }
    if (t == 1023) off[n] = sums[1023];
}

__global__ void scatter_kernel(const int* __restrict__ src, const int* __restrict__ dst,
                               const int* __restrict__ off, int* __restrict__ cursor,
                               int* __restrict__ esrc, int E) {
    int i = blockIdx.x * blockDim.x + threadIdx.x;
    if (i < E) {
        int d = dst[i];
        int pos = atomicAdd(&cursor[d], 1);
        esrc[off[d] + pos] = src[i];
    }
}

// ==================== softmax aggregation + residual ====================
// One wave per node, lane = channel. Online softmax over neighbors.
// h[n][c] = sum_j msg_j * exp(msg_j - max) / (sum exp + 1e-16) + x[n][c]
__global__ __launch_bounds__(256) void agg_kernel(const float* __restrict__ x,
                                                  const int* __restrict__ off,
                                                  const int* __restrict__ esrc,
                                                  float* __restrict__ h) {
    int node = blockIdx.x * 4 + (threadIdx.x >> 6);
    int lane = threadIdx.x & 63;
    if (node >= N_NODES) return;
    int jb = off[node], je = off[node + 1];
    float m = -INFINITY, s = 0.f, t = 0.f;
    for (int j = jb; j < je; j++) {
        int sv = esrc[j];
        float v = x[(size_t)sv * D_IN + lane];
        float msg = fmaxf(v, 0.f) + 1e-7f;
        float nm = fmaxf(m, msg);
        float c = __expf(m - nm);    // first iter: exp(-inf)=0
        float p = __expf(msg - nm);
        s = s * c + p;
        t = t * c + msg * p;
        m = nm;
    }
    float agg = t / (s + 1e-16f);    // deg==0 -> 0/(1e-16) = 0
    h[(size_t)node * D_IN + lane] = agg + x[(size_t)node * D_IN + lane];
}

// ==================== GEMM1: B[M,128] = A[M,64] @ W[64,128] + b ====================
__global__ __launch_bounds__(256) void gemm1_kernel(const float* __restrict__ A,
                                                    const float* __restrict__ W,
                                                    const float* __restrict__ bias,
                                                    float* __restrict__ Bout) {
    __shared__ float sW[64 * 128];  // 32 KB
    const int tid = threadIdx.x;
    {
        const float4* Wv = (const float4*)W;
        float4* sWv = (float4*)sW;
        #pragma unroll
        for (int i = tid; i < 64 * 128 / 4; i += 256) sWv[i] = Wv[i];
    }
    __syncthreads();
    const int tx = tid & 15;   // 16 col-groups of 8 -> 128 cols
    const int ty = tid >> 4;   // 16 row-groups of 4 -> 64 rows
    const int c0 = tx * 8;
    const int row0 = blockIdx.x * 64 + ty * 4;

    float acc[4][8];
    #pragma unroll
    for (int i = 0; i < 4; i++)
        #pragma unroll
        for (int j = 0; j < 8; j++) acc[i][j] = bias[c0 + j];

    for (int k = 0; k < 64; k += 4) {
        float a[4][4];
        #pragma unroll
        for (int i = 0; i < 4; i++) {
            int r = min(row0 + i, N_NODES - 1);
            float4 t4 = *(const float4*)&A[(size_t)r * 64 + k];
            a[i][0] = t4.x; a[i][1] = t4.y; a[i][2] = t4.z; a[i][3] = t4.w;
        }
        #pragma unroll
        for (int kk = 0; kk < 4; kk++) {
            float4 w0 = *(const float4*)&sW[(k + kk) * 128 + c0];
            float4 w1 = *(const float4*)&sW[(k + kk) * 128 + c0 + 4];
            #pragma unroll
            for (int i = 0; i < 4; i++) {
                float ai = a[i][kk];
                acc[i][0] = fmaf(ai, w0.x, acc[i][0]);
                acc[i][1] = fmaf(ai, w0.y, acc[i][1]);
                acc[i][2] = fmaf(ai, w0.z, acc[i][2]);
                acc[i][3] = fmaf(ai, w0.w, acc[i][3]);
                acc[i][4] = fmaf(ai, w1.x, acc[i][4]);
                acc[i][5] = fmaf(ai, w1.y, acc[i][5]);
                acc[i][6] = fmaf(ai, w1.z, acc[i][6]);
                acc[i][7] = fmaf(ai, w1.w, acc[i][7]);
            }
        }
    }
    #pragma unroll
    for (int i = 0; i < 4; i++) {
        int r = row0 + i;
        if (r < N_NODES) {
            float4 o0 = make_float4(acc[i][0], acc[i][1], acc[i][2], acc[i][3]);
            float4 o1 = make_float4(acc[i][4], acc[i][5], acc[i][6], acc[i][7]);
            *(float4*)&Bout[(size_t)r * 128 + c0]     = o0;
            *(float4*)&Bout[(size_t)r * 128 + c0 + 4] = o1;
        }
    }
}

// ==================== BN stats ====================
__global__ void bnstats_kernel(const float* __restrict__ B, float* __restrict__ S,
                               float* __restrict__ Q) {
    const int c = threadIdx.x;  // 128 channels
    const int rpb = (N_NODES + gridDim.x - 1) / gridDim.x;
    int r0 = blockIdx.x * rpb, r1 = min(r0 + rpb, N_NODES);
    float s = 0.f, q = 0.f;
    for (int r = r0; r < r1; r++) {
        float v = B[(size_t)r * D_HID + c];
        s += v; q += v * v;
    }
    atomicAdd(&S[c], s);
    atomicAdd(&Q[c], q);
}

__global__ void bnfin_kernel(const float* __restrict__ S, const float* __restrict__ Q,
                             const float* __restrict__ gamma, const float* __restrict__ beta,
                             float* __restrict__ ss) {
    int c = threadIdx.x;
    float mean = S[c] * (1.f / N_NODES);
    float var = fmaxf(Q[c] * (1.f / N_NODES) - mean * mean, 0.f);
    float sc = gamma[c] * rsqrtf(var + 1e-5f);
    ss[c] = sc;
    ss[D_HID + c] = beta[c] - mean * sc;
}

// ==================== GEMM2: out = relu(H*scale+shift) @ W2[128,64] + b2 (+mish) ====
__device__ __forceinline__ float mish_f(float v) {
    if (v > 30.f) return v;
    float u = __expf(v);
    float t = (u + 1.f) * (u + 1.f);
    return v * (t - 1.f) / (t + 1.f);  // = v * tanh(softplus(v)), exact identity
}

__global__ __launch_bounds__(256) void gemm2_kernel(const float* __restrict__ H,
                                                    const float* __restrict__ ss,
                                                    const float* __restrict__ W,
                                                    const float* __restrict__ bias,
                                                    float* __restrict__ out, int domish) {
    __shared__ float sW[128 * 64];  // 32 KB
    const int tid = threadIdx.x;
    {
        const float4* Wv = (const float4*)W;
        float4* sWv = (float4*)sW;
        #pragma unroll
        for (int i = tid; i < 128 * 64 / 4; i += 256) sWv[i] = Wv[i];
    }
    __syncthreads();
    const int tx = tid & 7;    // 8 col-groups of 8 -> 64 cols
    const int ty = tid >> 3;   // 32 row-groups of 4 -> 128 rows
    const int c0 = tx * 8;
    const int row0 = blockIdx.x * 128 + ty * 4;

    float acc[4][8];
    #pragma unroll
    for (int i = 0; i < 4; i++)
        #pragma unroll
        for (int j = 0; j < 8; j++) acc[i][j] = bias[c0 + j];

    for (int k = 0; k < 128; k += 4) {
        float4 sc4 = *(const float4*)&ss[k];
        float4 sh4 = *(const float4*)&ss[D_HID + k];
        float a[4][4];
        #pragma unroll
        for (int i = 0; i < 4; i++) {
            int r = min(row0 + i, N_NODES - 1);
            float4 t4 = *(const float4*)&H[(size_t)r * 128 + k];
            a[i][0] = fmaxf(fmaf(t4.x, sc4.x, sh4.x), 0.f);
            a[i][1] = fmaxf(fmaf(t4.y, sc4.y, sh4.y), 0.f);
            a[i][2] = fmaxf(fmaf(t4.z, sc4.z, sh4.z), 0.f);
            a[i][3] = fmaxf(fmaf(t4.w, sc4.w, sh4.w), 0.f);
        }
        #pragma unroll
        for (int kk = 0; kk < 4; kk++) {
            float4 w0 = *(const float4*)&sW[(k + kk) * 64 + c0];
            float4 w1 = *(const float4*)&sW[(k + kk) * 64 + c0 + 4];
            #pragma unroll
            for (int i = 0; i < 4; i++) {
                float ai = a[i][kk];
                acc[i][0] = fmaf(ai, w0.x, acc[i][0]);
                acc[i][1] = fmaf(ai, w0.y, acc[i][1]);
                acc[i][2] = fmaf(ai, w0.z, acc[i][2]);
                acc[i][3] = fmaf(ai, w0.w, acc[i][3]);
                acc[i][4] = fmaf(ai, w1.x, acc[i][4]);
                acc[i][5] = fmaf(ai, w1.y, acc[i][5]);
                acc[i][6] = fmaf(ai, w1.z, acc[i][6]);
                acc[i][7] = fmaf(ai, w1.w, acc[i][7]);
            }
        }
    }
    #pragma unroll
    for (int i = 0; i < 4; i++) {
        int r = row0 + i;
        if (r < N_NODES) {
            float v[8];
            #pragma unroll
            for (int j = 0; j < 8; j++) v[j] = domish ? mish_f(acc[i][j]) : acc[i][j];
            float4 o0 = make_float4(v[0], v[1], v[2], v[3]);
            float4 o1 = make_float4(v[4], v[5], v[6], v[7]);
            *(float4*)&out[(size_t)r * 64 + c0]     = o0;
            *(float4*)&out[(size_t)r * 64 + c0 + 4] = o1;
        }
    }
}

// ============================ launch ============================

extern "C" void kernel_launch(void* const* d_in, const int* in_sizes, int n_in,
                              void* d_out, int out_size, void* d_ws, size_t ws_size,
                              hipStream_t stream) {
    const float* x     = (const float*)d_in[0];
    const int*   ei    = (const int*)d_in[1];
    const float* W1    = (const float*)d_in[2];
    const float* b1    = (const float*)d_in[3];
    const float* gamma = (const float*)d_in[4];
    const float* beta  = (const float*)d_in[5];
    const float* W2    = (const float*)d_in[6];
    const float* b2    = (const float*)d_in[7];
    float* out = (float*)d_out;

    const int* src = ei;
    const int* dst = ei + N_EDGES;

    // workspace layout (256B-aligned slabs), ~55 MB total
    char* base = (char*)d_ws;
    size_t o = 0;
    auto take = [&](size_t bytes) -> char* {
        char* p = base + o;
        o = (o + bytes + 255) & ~(size_t)255;
        return p;
    };
    int* deg     = (int*)take((size_t)N_NODES * 4);
    int* cursor  = (int*)take((size_t)N_NODES * 4);
    int* off     = (int*)take((size_t)(N_NODES + 1) * 4);
    int* esrc    = (int*)take((size_t)N_EDGES * 4);
    float* bn    = (float*)take(512 * 4);  // S[128] Q[128] scale/shift[256]
    float* xbuf  = (float*)take((size_t)N_NODES * D_IN * 4);
    float* hbuf  = (float*)take((size_t)N_NODES * D_IN * 4);
    float* h1buf = (float*)take((size_t)N_NODES * D_HID * 4);

    // CSR build (once per call; dst is layer-invariant)
    hipMemsetAsync(deg, 0, (size_t)N_NODES * 4, stream);
    hipMemsetAsync(cursor, 0, (size_t)N_NODES * 4, stream);
    count_kernel<<<(N_EDGES + 255) / 256, 256, 0, stream>>>(dst, deg, N_EDGES);
    scan_kernel<<<1, 1024, 0, stream>>>(deg, off, N_NODES);
    scatter_kernel<<<(N_EDGES + 255) / 256, 256, 0, stream>>>(src, dst, off, cursor, esrc, N_EDGES);

    for (int L = 0; L < 4; L++) {
        const float* cx = (L == 0) ? x : xbuf;
        agg_kernel<<<N_NODES / 4, 256, 0, stream>>>(cx, off, esrc, hbuf);
        gemm1_kernel<<<(N_NODES + 63) / 64, 256, 0, stream>>>(
            hbuf, W1 + (size_t)L * D_IN * D_HID, b1 + (size_t)L * D_HID, h1buf);
        hipMemsetAsync(bn, 0, 256 * 4, stream);
        bnstats_kernel<<<128, 128, 0, stream>>>(h1buf, bn, bn + 128);
        bnfin_kernel<<<1, 128, 0, stream>>>(bn, bn + 128, gamma + (size_t)L * D_HID,
                                            beta + (size_t)L * D_HID, bn + 256);
        gemm2_kernel<<<(N_NODES + 127) / 128, 256, 0, stream>>>(
            h1buf, bn + 256, W2 + (size_t)L * D_HID * D_IN, b2 + (size_t)L * D_IN,
            (L < 3) ? xbuf : out, (L < 3) ? 1 : 0);
    }
}

// Round 2
// 807.488 us; speedup vs baseline: 1.4019x; 1.4019x over previous
//
#include <hip/hip_runtime.h>
#include <math.h>

#define N_NODES 50000
#define N_EDGES 800000
#define D_IN 64
#define D_HID 128

// ============================ CSR build ============================

__global__ void count_kernel(const int* __restrict__ dst, int* __restrict__ deg, int E) {
    int i = blockIdx.x * blockDim.x + threadIdx.x;
    if (i < E) atomicAdd(&deg[dst[i]], 1);
}

// Single-block exclusive scan over deg[n] -> off[n+1]
__global__ void scan_kernel(const int* __restrict__ deg, int* __restrict__ off, int n) {
    __shared__ int sums[1024];
    const int t = threadIdx.x;
    const int per = (n + 1023) / 1024;  // 49 for n=50000
    int start = t * per, end = min(start + per, n);
    int s = 0;
    for (int i = start; i < end; i++) s += deg[i];
    sums[t] = s;
    __syncthreads();
    for (int o = 1; o < 1024; o <<= 1) {
        int v = 0;
        if (t >= o) v = sums[t - o];
        __syncthreads();
        sums[t] += v;
        __syncthreads();
    }
    int run = (t == 0) ? 0 : sums[t - 1];
    for (int i = start; i < end; i++) { off[i] = run; run += deg[i]; }
    if (t == 1023) off[n] = sums[1023];
}

__global__ void scatter_kernel(const int* __restrict__ src, const int* __restrict__ dst,
                               const int* __restrict__ off, int* __restrict__ cursor,
                               int* __restrict__ esrc, int E) {
    int i = blockIdx.x * blockDim.x + threadIdx.x;
    if (i < E) {
        int d = dst[i];
        int pos = atomicAdd(&cursor[d], 1);
        esrc[off[d] + pos] = src[i];
    }
}

// ==================== softmax aggregation + residual ====================
// One wave per node, lane = channel. Online softmax over neighbors.
__global__ __launch_bounds__(256) void agg_kernel(const float* __restrict__ x,
                                                  const int* __restrict__ off,
                                                  const int* __restrict__ esrc,
                                                  float* __restrict__ h) {
    int node = blockIdx.x * 4 + (threadIdx.x >> 6);
    int lane = threadIdx.x & 63;
    if (node >= N_NODES) return;
    int jb = off[node], je = off[node + 1];
    float m = -INFINITY, s = 0.f, t = 0.f;
    for (int j = jb; j < je; j++) {
        int sv = esrc[j];
        float v = x[(size_t)sv * D_IN + lane];
        float msg = fmaxf(v, 0.f) + 1e-7f;
        float nm = fmaxf(m, msg);
        float c = __expf(m - nm);    // first iter: exp(-inf)=0
        float p = __expf(msg - nm);
        s = s * c + p;
        t = t * c + msg * p;
        m = nm;
    }
    float agg = t / (s + 1e-16f);    // deg==0 -> 0/(1e-16) = 0
    h[(size_t)node * D_IN + lane] = agg + x[(size_t)node * D_IN + lane];
}

// ==================== GEMM1 + fused BN stats ====================
// B[M,128] = A[M,64] @ W[64,128] + b; also accumulates per-channel
// sum/sumsq into S/Q via block-level LDS reduction + one atomicAdd each.
__global__ __launch_bounds__(256) void gemm1_kernel(const float* __restrict__ A,
                                                    const float* __restrict__ W,
                                                    const float* __restrict__ bias,
                                                    float* __restrict__ Bout,
                                                    float* __restrict__ S,
                                                    float* __restrict__ Q) {
    __shared__ float sW[64 * 128];  // 32 KB; reused as reduction space in epilogue
    const int tid = threadIdx.x;
    {
        const float4* Wv = (const float4*)W;
        float4* sWv = (float4*)sW;
        #pragma unroll
        for (int i = tid; i < 64 * 128 / 4; i += 256) sWv[i] = Wv[i];
    }
    __syncthreads();
    const int tx = tid & 15;   // 16 col-groups of 8 -> 128 cols
    const int ty = tid >> 4;   // 16 row-groups of 4 -> 64 rows
    const int c0 = tx * 8;
    const int row0 = blockIdx.x * 64 + ty * 4;

    float acc[4][8];
    #pragma unroll
    for (int i = 0; i < 4; i++)
        #pragma unroll
        for (int j = 0; j < 8; j++) acc[i][j] = bias[c0 + j];

    for (int k = 0; k < 64; k += 4) {
        float a[4][4];
        #pragma unroll
        for (int i = 0; i < 4; i++) {
            int r = min(row0 + i, N_NODES - 1);
            float4 t4 = *(const float4*)&A[(size_t)r * 64 + k];
            a[i][0] = t4.x; a[i][1] = t4.y; a[i][2] = t4.z; a[i][3] = t4.w;
        }
        #pragma unroll
        for (int kk = 0; kk < 4; kk++) {
            float4 w0 = *(const float4*)&sW[(k + kk) * 128 + c0];
            float4 w1 = *(const float4*)&sW[(k + kk) * 128 + c0 + 4];
            #pragma unroll
            for (int i = 0; i < 4; i++) {
                float ai = a[i][kk];
                acc[i][0] = fmaf(ai, w0.x, acc[i][0]);
                acc[i][1] = fmaf(ai, w0.y, acc[i][1]);
                acc[i][2] = fmaf(ai, w0.z, acc[i][2]);
                acc[i][3] = fmaf(ai, w0.w, acc[i][3]);
                acc[i][4] = fmaf(ai, w1.x, acc[i][4]);
                acc[i][5] = fmaf(ai, w1.y, acc[i][5]);
                acc[i][6] = fmaf(ai, w1.z, acc[i][6]);
                acc[i][7] = fmaf(ai, w1.w, acc[i][7]);
            }
        }
    }
    // store result tile
    #pragma unroll
    for (int i = 0; i < 4; i++) {
        int r = row0 + i;
        if (r < N_NODES) {
            float4 o0 = make_float4(acc[i][0], acc[i][1], acc[i][2], acc[i][3]);
            float4 o1 = make_float4(acc[i][4], acc[i][5], acc[i][6], acc[i][7]);
            *(float4*)&Bout[(size_t)r * 128 + c0]     = o0;
            *(float4*)&Bout[(size_t)r * 128 + c0 + 4] = o1;
        }
    }
    // fused BN stats: per-thread partials over valid rows -> LDS -> atomics
    float s8[8], q8[8];
    #pragma unroll
    for (int j = 0; j < 8; j++) { s8[j] = 0.f; q8[j] = 0.f; }
    #pragma unroll
    for (int i = 0; i < 4; i++) {
        if (row0 + i < N_NODES) {
            #pragma unroll
            for (int j = 0; j < 8; j++) {
                float v = acc[i][j];
                s8[j] += v; q8[j] += v * v;
            }
        }
    }
    __syncthreads();  // sW no longer read by main loop
    float* sSum = sW;              // [16][128]
    float* sSq  = sW + 16 * 128;   // [16][128]
    #pragma unroll
    for (int j = 0; j < 8; j++) {
        sSum[ty * 128 + c0 + j] = s8[j];
        sSq[ty * 128 + c0 + j]  = q8[j];
    }
    __syncthreads();
    if (tid < 128) {
        float s = 0.f;
        #pragma unroll
        for (int t = 0; t < 16; t++) s += sSum[t * 128 + tid];
        atomicAdd(&S[tid], s);
    } else {
        int c = tid - 128;
        float q = 0.f;
        #pragma unroll
        for (int t = 0; t < 16; t++) q += sSq[t * 128 + c];
        atomicAdd(&Q[c], q);
    }
}

__global__ void bnfin_kernel(const float* __restrict__ S, const float* __restrict__ Q,
                             const float* __restrict__ gamma, const float* __restrict__ beta,
                             float* __restrict__ ss) {
    int c = threadIdx.x;
    float mean = S[c] * (1.f / N_NODES);
    float var = fmaxf(Q[c] * (1.f / N_NODES) - mean * mean, 0.f);
    float sc = gamma[c] * rsqrtf(var + 1e-5f);
    ss[c] = sc;
    ss[D_HID + c] = beta[c] - mean * sc;
}

// ==================== GEMM2: out = relu(H*scale+shift) @ W2[128,64] + b2 (+mish) ====
__device__ __forceinline__ float mish_f(float v) {
    if (v > 30.f) return v;
    float u = __expf(v);
    float t = (u + 1.f) * (u + 1.f);
    return v * (t - 1.f) / (t + 1.f);  // = v * tanh(softplus(v)), exact identity
}

__global__ __launch_bounds__(256) void gemm2_kernel(const float* __restrict__ H,
                                                    const float* __restrict__ ss,
                                                    const float* __restrict__ W,
                                                    const float* __restrict__ bias,
                                                    float* __restrict__ out, int domish) {
    __shared__ float sW[128 * 64];  // 32 KB
    const int tid = threadIdx.x;
    {
        const float4* Wv = (const float4*)W;
        float4* sWv = (float4*)sW;
        #pragma unroll
        for (int i = tid; i < 128 * 64 / 4; i += 256) sWv[i] = Wv[i];
    }
    __syncthreads();
    const int tx = tid & 7;    // 8 col-groups of 8 -> 64 cols
    const int ty = tid >> 3;   // 32 row-groups of 4 -> 128 rows
    const int c0 = tx * 8;
    const int row0 = blockIdx.x * 128 + ty * 4;

    float acc[4][8];
    #pragma unroll
    for (int i = 0; i < 4; i++)
        #pragma unroll
        for (int j = 0; j < 8; j++) acc[i][j] = bias[c0 + j];

    for (int k = 0; k < 128; k += 4) {
        float4 sc4 = *(const float4*)&ss[k];
        float4 sh4 = *(const float4*)&ss[D_HID + k];
        float a[4][4];
        #pragma unroll
        for (int i = 0; i < 4; i++) {
            int r = min(row0 + i, N_NODES - 1);
            float4 t4 = *(const float4*)&H[(size_t)r * 128 + k];
            a[i][0] = fmaxf(fmaf(t4.x, sc4.x, sh4.x), 0.f);
            a[i][1] = fmaxf(fmaf(t4.y, sc4.y, sh4.y), 0.f);
            a[i][2] = fmaxf(fmaf(t4.z, sc4.z, sh4.z), 0.f);
            a[i][3] = fmaxf(fmaf(t4.w, sc4.w, sh4.w), 0.f);
        }
        #pragma unroll
        for (int kk = 0; kk < 4; kk++) {
            float4 w0 = *(const float4*)&sW[(k + kk) * 64 + c0];
            float4 w1 = *(const float4*)&sW[(k + kk) * 64 + c0 + 4];
            #pragma unroll
            for (int i = 0; i < 4; i++) {
                float ai = a[i][kk];
                acc[i][0] = fmaf(ai, w0.x, acc[i][0]);
                acc[i][1] = fmaf(ai, w0.y, acc[i][1]);
                acc[i][2] = fmaf(ai, w0.z, acc[i][2]);
                acc[i][3] = fmaf(ai, w0.w, acc[i][3]);
                acc[i][4] = fmaf(ai, w1.x, acc[i][4]);
                acc[i][5] = fmaf(ai, w1.y, acc[i][5]);
                acc[i][6] = fmaf(ai, w1.z, acc[i][6]);
                acc[i][7] = fmaf(ai, w1.w, acc[i][7]);
            }
        }
    }
    #pragma unroll
    for (int i = 0; i < 4; i++) {
        int r = row0 + i;
        if (r < N_NODES) {
            float v[8];
            #pragma unroll
            for (int j = 0; j < 8; j++) v[j] = domish ? mish_f(acc[i][j]) : acc[i][j];
            float4 o0 = make_float4(v[0], v[1], v[2], v[3]);
            float4 o1 = make_float4(v[4], v[5], v[6], v[7]);
            *(float4*)&out[(size_t)r * 64 + c0]     = o0;
            *(float4*)&out[(size_t)r * 64 + c0 + 4] = o1;
        }
    }
}

// ============================ launch ============================

extern "C" void kernel_launch(void* const* d_in, const int* in_sizes, int n_in,
                              void* d_out, int out_size, void* d_ws, size_t ws_size,
                              hipStream_t stream) {
    const float* x     = (const float*)d_in[0];
    const int*   ei    = (const int*)d_in[1];
    const float* W1    = (const float*)d_in[2];
    const float* b1    = (const float*)d_in[3];
    const float* gamma = (const float*)d_in[4];
    const float* beta  = (const float*)d_in[5];
    const float* W2    = (const float*)d_in[6];
    const float* b2    = (const float*)d_in[7];
    float* out = (float*)d_out;

    const int* src = ei;
    const int* dst = ei + N_EDGES;

    char* base = (char*)d_ws;
    size_t o = 0;
    auto take = [&](size_t bytes) -> char* {
        char* p = base + o;
        o = (o + bytes + 255) & ~(size_t)255;
        return p;
    };
    int* deg     = (int*)take((size_t)N_NODES * 4);
    int* cursor  = (int*)take((size_t)N_NODES * 4);
    int* off     = (int*)take((size_t)(N_NODES + 1) * 4);
    int* esrc    = (int*)take((size_t)N_EDGES * 4);
    float* bn    = (float*)take(512 * 4);  // S[128] Q[128] scale/shift[256]
    float* xbuf  = (float*)take((size_t)N_NODES * D_IN * 4);
    float* hbuf  = (float*)take((size_t)N_NODES * D_IN * 4);
    float* h1buf = (float*)take((size_t)N_NODES * D_HID * 4);

    // CSR build (once per call; dst is layer-invariant)
    hipMemsetAsync(deg, 0, (size_t)N_NODES * 4, stream);
    hipMemsetAsync(cursor, 0, (size_t)N_NODES * 4, stream);
    count_kernel<<<(N_EDGES + 255) / 256, 256, 0, stream>>>(dst, deg, N_EDGES);
    scan_kernel<<<1, 1024, 0, stream>>>(deg, off, N_NODES);
    scatter_kernel<<<(N_EDGES + 255) / 256, 256, 0, stream>>>(src, dst, off, cursor, esrc, N_EDGES);

    for (int L = 0; L < 4; L++) {
        const float* cx = (L == 0) ? x : xbuf;
        agg_kernel<<<N_NODES / 4, 256, 0, stream>>>(cx, off, esrc, hbuf);
        hipMemsetAsync(bn, 0, 256 * 4, stream);  // zero S/Q before gemm1's fused stats
        gemm1_kernel<<<(N_NODES + 63) / 64, 256, 0, stream>>>(
            hbuf, W1 + (size_t)L * D_IN * D_HID, b1 + (size_t)L * D_HID, h1buf,
            bn, bn + 128);
        bnfin_kernel<<<1, 128, 0, stream>>>(bn, bn + 128, gamma + (size_t)L * D_HID,
                                            beta + (size_t)L * D_HID, bn + 256);
        gemm2_kernel<<<(N_NODES + 127) / 128, 256, 0, stream>>>(
            h1buf, bn + 256, W2 + (size_t)L * D_HID * D_IN, b2 + (size_t)L * D_IN,
            (L < 3) ? xbuf : out, (L < 3) ? 1 : 0);
    }
}

// Round 3
// 619.549 us; speedup vs baseline: 1.8272x; 1.3033x over previous
//
#include <hip/hip_runtime.h>
#include <math.h>

#define N_NODES 50000
#define N_EDGES 800000
#define D_IN 64
#define D_HID 128

// ============================ CSR build ============================

__global__ void count_kernel(const int* __restrict__ dst, int* __restrict__ deg, int E) {
    int i = blockIdx.x * blockDim.x + threadIdx.x;
    if (i < E) atomicAdd(&deg[dst[i]], 1);
}

// Single-block exclusive scan over deg[n] -> off[n+1]
__global__ void scan_kernel(const int* __restrict__ deg, int* __restrict__ off, int n) {
    __shared__ int sums[1024];
    const int t = threadIdx.x;
    const int per = (n + 1023) / 1024;  // 49 for n=50000
    int start = t * per, end = min(start + per, n);
    int s = 0;
    for (int i = start; i < end; i++) s += deg[i];
    sums[t] = s;
    __syncthreads();
    for (int o = 1; o < 1024; o <<= 1) {
        int v = 0;
        if (t >= o) v = sums[t - o];
        __syncthreads();
        sums[t] += v;
        __syncthreads();
    }
    int run = (t == 0) ? 0 : sums[t - 1];
    for (int i = start; i < end; i++) { off[i] = run; run += deg[i]; }
    if (t == 1023) off[n] = sums[1023];
}

__global__ void scatter_kernel(const int* __restrict__ src, const int* __restrict__ dst,
                               const int* __restrict__ off, int* __restrict__ cursor,
                               int* __restrict__ esrc, int E) {
    int i = blockIdx.x * blockDim.x + threadIdx.x;
    if (i < E) {
        int d = dst[i];
        int pos = atomicAdd(&cursor[d], 1);
        esrc[off[d] + pos] = src[i];
    }
}

// ==================== softmax aggregation + residual ====================
// One wave per node, lane = channel. No-max softmax (values are O(1), exp is
// safe in fp32; identical math to max-subtracted form). 4-edge unroll gives
// 4 outstanding row-gathers per wave instead of 1 (latency-bound fix).
__global__ __launch_bounds__(256) void agg_kernel(const float* __restrict__ x,
                                                  const int* __restrict__ off,
                                                  const int* __restrict__ esrc,
                                                  float* __restrict__ h) {
    int node = blockIdx.x * 4 + (threadIdx.x >> 6);
    int lane = threadIdx.x & 63;
    if (node >= N_NODES) return;
    float xn = x[(size_t)node * D_IN + lane];  // residual, load early
    int jb = off[node], je = off[node + 1];
    float s = 0.f, t = 0.f;
    int j = jb;
    for (; j + 4 <= je; j += 4) {
        int i0 = esrc[j], i1 = esrc[j + 1], i2 = esrc[j + 2], i3 = esrc[j + 3];
        float v0 = x[(size_t)i0 * D_IN + lane];
        float v1 = x[(size_t)i1 * D_IN + lane];
        float v2 = x[(size_t)i2 * D_IN + lane];
        float v3 = x[(size_t)i3 * D_IN + lane];
        float m0 = fmaxf(v0, 0.f) + 1e-7f;
        float m1 = fmaxf(v1, 0.f) + 1e-7f;
        float m2 = fmaxf(v2, 0.f) + 1e-7f;
        float m3 = fmaxf(v3, 0.f) + 1e-7f;
        float p0 = __expf(m0), p1 = __expf(m1), p2 = __expf(m2), p3 = __expf(m3);
        s += (p0 + p1) + (p2 + p3);
        t = fmaf(m0, p0, t);
        t = fmaf(m1, p1, t);
        t = fmaf(m2, p2, t);
        t = fmaf(m3, p3, t);
    }
    for (; j < je; j++) {
        int sv = esrc[j];
        float v = x[(size_t)sv * D_IN + lane];
        float msg = fmaxf(v, 0.f) + 1e-7f;
        float p = __expf(msg);
        s += p;
        t = fmaf(msg, p, t);
    }
    float agg = t / (s + 1e-16f);    // deg==0 -> 0/(1e-16) = 0
    h[(size_t)node * D_IN + lane] = agg + xn;
}

// ==================== GEMM1 + fused BN stats ====================
// B[M,128] = A[M,64] @ W[64,128] + b; also accumulates per-channel
// sum/sumsq into S/Q via block-level LDS reduction + one atomicAdd each.
__global__ __launch_bounds__(256) void gemm1_kernel(const float* __restrict__ A,
                                                    const float* __restrict__ W,
                                                    const float* __restrict__ bias,
                                                    float* __restrict__ Bout,
                                                    float* __restrict__ S,
                                                    float* __restrict__ Q) {
    __shared__ float sW[64 * 128];  // 32 KB; reused as reduction space in epilogue
    const int tid = threadIdx.x;
    {
        const float4* Wv = (const float4*)W;
        float4* sWv = (float4*)sW;
        #pragma unroll
        for (int i = tid; i < 64 * 128 / 4; i += 256) sWv[i] = Wv[i];
    }
    __syncthreads();
    const int tx = tid & 15;   // 16 col-groups of 8 -> 128 cols
    const int ty = tid >> 4;   // 16 row-groups of 4 -> 64 rows
    const int c0 = tx * 8;
    const int row0 = blockIdx.x * 64 + ty * 4;

    float acc[4][8];
    #pragma unroll
    for (int i = 0; i < 4; i++)
        #pragma unroll
        for (int j = 0; j < 8; j++) acc[i][j] = bias[c0 + j];

    for (int k = 0; k < 64; k += 4) {
        float a[4][4];
        #pragma unroll
        for (int i = 0; i < 4; i++) {
            int r = min(row0 + i, N_NODES - 1);
            float4 t4 = *(const float4*)&A[(size_t)r * 64 + k];
            a[i][0] = t4.x; a[i][1] = t4.y; a[i][2] = t4.z; a[i][3] = t4.w;
        }
        #pragma unroll
        for (int kk = 0; kk < 4; kk++) {
            float4 w0 = *(const float4*)&sW[(k + kk) * 128 + c0];
            float4 w1 = *(const float4*)&sW[(k + kk) * 128 + c0 + 4];
            #pragma unroll
            for (int i = 0; i < 4; i++) {
                float ai = a[i][kk];
                acc[i][0] = fmaf(ai, w0.x, acc[i][0]);
                acc[i][1] = fmaf(ai, w0.y, acc[i][1]);
                acc[i][2] = fmaf(ai, w0.z, acc[i][2]);
                acc[i][3] = fmaf(ai, w0.w, acc[i][3]);
                acc[i][4] = fmaf(ai, w1.x, acc[i][4]);
                acc[i][5] = fmaf(ai, w1.y, acc[i][5]);
                acc[i][6] = fmaf(ai, w1.z, acc[i][6]);
                acc[i][7] = fmaf(ai, w1.w, acc[i][7]);
            }
        }
    }
    // store result tile
    #pragma unroll
    for (int i = 0; i < 4; i++) {
        int r = row0 + i;
        if (r < N_NODES) {
            float4 o0 = make_float4(acc[i][0], acc[i][1], acc[i][2], acc[i][3]);
            float4 o1 = make_float4(acc[i][4], acc[i][5], acc[i][6], acc[i][7]);
            *(float4*)&Bout[(size_t)r * 128 + c0]     = o0;
            *(float4*)&Bout[(size_t)r * 128 + c0 + 4] = o1;
        }
    }
    // fused BN stats: per-thread partials over valid rows -> LDS -> atomics
    float s8[8], q8[8];
    #pragma unroll
    for (int j = 0; j < 8; j++) { s8[j] = 0.f; q8[j] = 0.f; }
    #pragma unroll
    for (int i = 0; i < 4; i++) {
        if (row0 + i < N_NODES) {
            #pragma unroll
            for (int j = 0; j < 8; j++) {
                float v = acc[i][j];
                s8[j] += v; q8[j] += v * v;
            }
        }
    }
    __syncthreads();  // sW no longer read by main loop
    float* sSum = sW;              // [16][128]
    float* sSq  = sW + 16 * 128;   // [16][128]
    #pragma unroll
    for (int j = 0; j < 8; j++) {
        sSum[ty * 128 + c0 + j] = s8[j];
        sSq[ty * 128 + c0 + j]  = q8[j];
    }
    __syncthreads();
    if (tid < 128) {
        float s = 0.f;
        #pragma unroll
        for (int t = 0; t < 16; t++) s += sSum[t * 128 + tid];
        atomicAdd(&S[tid], s);
    } else {
        int c = tid - 128;
        float q = 0.f;
        #pragma unroll
        for (int t = 0; t < 16; t++) q += sSq[t * 128 + c];
        atomicAdd(&Q[c], q);
    }
}

__global__ void bnfin_kernel(const float* __restrict__ S, const float* __restrict__ Q,
                             const float* __restrict__ gamma, const float* __restrict__ beta,
                             float* __restrict__ ss) {
    int c = threadIdx.x;
    float mean = S[c] * (1.f / N_NODES);
    float var = fmaxf(Q[c] * (1.f / N_NODES) - mean * mean, 0.f);
    float sc = gamma[c] * rsqrtf(var + 1e-5f);
    ss[c] = sc;
    ss[D_HID + c] = beta[c] - mean * sc;
}

// ==================== GEMM2: out = relu(H*scale+shift) @ W2[128,64] + b2 (+mish) ====
__device__ __forceinline__ float mish_f(float v) {
    if (v > 30.f) return v;
    float u = __expf(v);
    float t = (u + 1.f) * (u + 1.f);
    return v * (t - 1.f) / (t + 1.f);  // = v * tanh(softplus(v)), exact identity
}

__global__ __launch_bounds__(256) void gemm2_kernel(const float* __restrict__ H,
                                                    const float* __restrict__ ss,
                                                    const float* __restrict__ W,
                                                    const float* __restrict__ bias,
                                                    float* __restrict__ out, int domish) {
    __shared__ float sW[128 * 64];  // 32 KB
    const int tid = threadIdx.x;
    {
        const float4* Wv = (const float4*)W;
        float4* sWv = (float4*)sW;
        #pragma unroll
        for (int i = tid; i < 128 * 64 / 4; i += 256) sWv[i] = Wv[i];
    }
    __syncthreads();
    const int tx = tid & 7;    // 8 col-groups of 8 -> 64 cols
    const int ty = tid >> 3;   // 32 row-groups of 4 -> 128 rows
    const int c0 = tx * 8;
    const int row0 = blockIdx.x * 128 + ty * 4;

    float acc[4][8];
    #pragma unroll
    for (int i = 0; i < 4; i++)
        #pragma unroll
        for (int j = 0; j < 8; j++) acc[i][j] = bias[c0 + j];

    for (int k = 0; k < 128; k += 4) {
        float4 sc4 = *(const float4*)&ss[k];
        float4 sh4 = *(const float4*)&ss[D_HID + k];
        float a[4][4];
        #pragma unroll
        for (int i = 0; i < 4; i++) {
            int r = min(row0 + i, N_NODES - 1);
            float4 t4 = *(const float4*)&H[(size_t)r * 128 + k];
            a[i][0] = fmaxf(fmaf(t4.x, sc4.x, sh4.x), 0.f);
            a[i][1] = fmaxf(fmaf(t4.y, sc4.y, sh4.y), 0.f);
            a[i][2] = fmaxf(fmaf(t4.z, sc4.z, sh4.z), 0.f);
            a[i][3] = fmaxf(fmaf(t4.w, sc4.w, sh4.w), 0.f);
        }
        #pragma unroll
        for (int kk = 0; kk < 4; kk++) {
            float4 w0 = *(const float4*)&sW[(k + kk) * 64 + c0];
            float4 w1 = *(const float4*)&sW[(k + kk) * 64 + c0 + 4];
            #pragma unroll
            for (int i = 0; i < 4; i++) {
                float ai = a[i][kk];
                acc[i][0] = fmaf(ai, w0.x, acc[i][0]);
                acc[i][1] = fmaf(ai, w0.y, acc[i][1]);
                acc[i][2] = fmaf(ai, w0.z, acc[i][2]);
                acc[i][3] = fmaf(ai, w0.w, acc[i][3]);
                acc[i][4] = fmaf(ai, w1.x, acc[i][4]);
                acc[i][5] = fmaf(ai, w1.y, acc[i][5]);
                acc[i][6] = fmaf(ai, w1.z, acc[i][6]);
                acc[i][7] = fmaf(ai, w1.w, acc[i][7]);
            }
        }
    }
    #pragma unroll
    for (int i = 0; i < 4; i++) {
        int r = row0 + i;
        if (r < N_NODES) {
            float v[8];
            #pragma unroll
            for (int j = 0; j < 8; j++) v[j] = domish ? mish_f(acc[i][j]) : acc[i][j];
            float4 o0 = make_float4(v[0], v[1], v[2], v[3]);
            float4 o1 = make_float4(v[4], v[5], v[6], v[7]);
            *(float4*)&out[(size_t)r * 64 + c0]     = o0;
            *(float4*)&out[(size_t)r * 64 + c0 + 4] = o1;
        }
    }
}

// ============================ launch ============================

extern "C" void kernel_launch(void* const* d_in, const int* in_sizes, int n_in,
                              void* d_out, int out_size, void* d_ws, size_t ws_size,
                              hipStream_t stream) {
    const float* x     = (const float*)d_in[0];
    const int*   ei    = (const int*)d_in[1];
    const float* W1    = (const float*)d_in[2];
    const float* b1    = (const float*)d_in[3];
    const float* gamma = (const float*)d_in[4];
    const float* beta  = (const float*)d_in[5];
    const float* W2    = (const float*)d_in[6];
    const float* b2    = (const float*)d_in[7];
    float* out = (float*)d_out;

    const int* src = ei;
    const int* dst = ei + N_EDGES;

    char* base = (char*)d_ws;
    size_t o = 0;
    auto take = [&](size_t bytes) -> char* {
        char* p = base + o;
        o = (o + bytes + 255) & ~(size_t)255;
        return p;
    };
    int* deg     = (int*)take((size_t)N_NODES * 4);
    int* cursor  = (int*)take((size_t)N_NODES * 4);
    int* off     = (int*)take((size_t)(N_NODES + 1) * 4);
    int* esrc    = (int*)take((size_t)N_EDGES * 4);
    float* bn    = (float*)take(512 * 4);  // S[128] Q[128] scale/shift[256]
    float* xbuf  = (float*)take((size_t)N_NODES * D_IN * 4);
    float* hbuf  = (float*)take((size_t)N_NODES * D_IN * 4);
    float* h1buf = (float*)take((size_t)N_NODES * D_HID * 4);

    // CSR build (once per call; dst is layer-invariant)
    hipMemsetAsync(deg, 0, (size_t)N_NODES * 4, stream);
    hipMemsetAsync(cursor, 0, (size_t)N_NODES * 4, stream);
    count_kernel<<<(N_EDGES + 255) / 256, 256, 0, stream>>>(dst, deg, N_EDGES);
    scan_kernel<<<1, 1024, 0, stream>>>(deg, off, N_NODES);
    scatter_kernel<<<(N_EDGES + 255) / 256, 256, 0, stream>>>(src, dst, off, cursor, esrc, N_EDGES);

    for (int L = 0; L < 4; L++) {
        const float* cx = (L == 0) ? x : xbuf;
        agg_kernel<<<N_NODES / 4, 256, 0, stream>>>(cx, off, esrc, hbuf);
        hipMemsetAsync(bn, 0, 256 * 4, stream);  // zero S/Q before gemm1's fused stats
        gemm1_kernel<<<(N_NODES + 63) / 64, 256, 0, stream>>>(
            hbuf, W1 + (size_t)L * D_IN * D_HID, b1 + (size_t)L * D_HID, h1buf,
            bn, bn + 128);
        bnfin_kernel<<<1, 128, 0, stream>>>(bn, bn + 128, gamma + (size_t)L * D_HID,
                                            beta + (size_t)L * D_HID, bn + 256);
        gemm2_kernel<<<(N_NODES + 127) / 128, 256, 0, stream>>>(
            h1buf, bn + 256, W2 + (size_t)L * D_HID * D_IN, b2 + (size_t)L * D_IN,
            (L < 3) ? xbuf : out, (L < 3) ? 1 : 0);
    }
}

// Round 4
// 534.005 us; speedup vs baseline: 2.1199x; 1.1602x over previous
//
#include <hip/hip_runtime.h>
#include <math.h>

#define N_NODES 50000
#define N_EDGES 800000
#define D_IN 64
#define D_HID 128
#define SCAN_B 256
#define N_SB ((N_NODES + SCAN_B - 1) / SCAN_B)  // 196

// ============================ CSR build ============================

__global__ void count_kernel(const int* __restrict__ dst, int* __restrict__ deg, int E) {
    int i = blockIdx.x * blockDim.x + threadIdx.x;
    if (i < E) atomicAdd(&deg[dst[i]], 1);
}

// Phase A: per-block sums of deg (coalesced)
__global__ __launch_bounds__(SCAN_B) void scan_reduce_kernel(const int* __restrict__ deg,
                                                             int* __restrict__ bsum) {
    __shared__ int s[SCAN_B];
    int i = blockIdx.x * SCAN_B + threadIdx.x;
    int v = (i < N_NODES) ? deg[i] : 0;
    s[threadIdx.x] = v;
    __syncthreads();
    #pragma unroll
    for (int o = SCAN_B / 2; o > 0; o >>= 1) {
        if (threadIdx.x < o) s[threadIdx.x] += s[threadIdx.x + o];
        __syncthreads();
    }
    if (threadIdx.x == 0) bsum[blockIdx.x] = s[0];
}

// Phase B: single small block — exclusive scan of the 196 block sums
__global__ __launch_bounds__(SCAN_B) void scan_sums_kernel(const int* __restrict__ bsum,
                                                           int* __restrict__ boff) {
    __shared__ int s[SCAN_B];
    int t = threadIdx.x;
    int v = (t < N_SB) ? bsum[t] : 0;
    s[t] = v;
    __syncthreads();
    #pragma unroll
    for (int o = 1; o < SCAN_B; o <<= 1) {
        int u = (t >= o) ? s[t - o] : 0;
        __syncthreads();
        s[t] += u;
        __syncthreads();
    }
    if (t < N_SB) boff[t] = s[t] - v;  // exclusive
}

// Phase C: per-block scan + block offset -> off[i]; last element writes off[n]
__global__ __launch_bounds__(SCAN_B) void scan_write_kernel(const int* __restrict__ deg,
                                                            const int* __restrict__ boff,
                                                            int* __restrict__ off) {
    __shared__ int s[SCAN_B];
    int t = threadIdx.x;
    int i = blockIdx.x * SCAN_B + t;
    int v = (i < N_NODES) ? deg[i] : 0;
    s[t] = v;
    __syncthreads();
    #pragma unroll
    for (int o = 1; o < SCAN_B; o <<= 1) {
        int u = (t >= o) ? s[t - o] : 0;
        __syncthreads();
        s[t] += u;
        __syncthreads();
    }
    int incl = s[t] + boff[blockIdx.x];
    if (i < N_NODES) off[i] = incl - v;
    if (i == N_NODES - 1) off[N_NODES] = incl;
}

__global__ void scatter_kernel(const int* __restrict__ src, const int* __restrict__ dst,
                               const int* __restrict__ off, int* __restrict__ cursor,
                               int* __restrict__ esrc, int E) {
    int i = blockIdx.x * blockDim.x + threadIdx.x;
    if (i < E) {
        int d = dst[i];
        int pos = atomicAdd(&cursor[d], 1);
        esrc[off[d] + pos] = src[i];
    }
}

// ==================== softmax aggregation + residual ====================
// One wave per node, lane = channel. No-max softmax (values O(1), fp32-safe;
// identical math to max-subtracted form). 8-edge unroll -> 8 outstanding
// row-gathers per wave (latency-bound fix).
__global__ __launch_bounds__(256) void agg_kernel(const float* __restrict__ x,
                                                  const int* __restrict__ off,
                                                  const int* __restrict__ esrc,
                                                  float* __restrict__ h) {
    int node = blockIdx.x * 4 + (threadIdx.x >> 6);
    int lane = threadIdx.x & 63;
    if (node >= N_NODES) return;
    float xn = x[(size_t)node * D_IN + lane];  // residual, load early
    int jb = off[node], je = off[node + 1];
    float s = 0.f, t = 0.f;
    int j = jb;
    for (; j + 8 <= je; j += 8) {
        int idx[8];
        #pragma unroll
        for (int u = 0; u < 8; u++) idx[u] = esrc[j + u];
        float v[8];
        #pragma unroll
        for (int u = 0; u < 8; u++) v[u] = x[(size_t)idx[u] * D_IN + lane];
        #pragma unroll
        for (int u = 0; u < 8; u++) {
            float msg = fmaxf(v[u], 0.f) + 1e-7f;
            float p = __expf(msg);
            s += p;
            t = fmaf(msg, p, t);
        }
    }
    for (; j + 4 <= je; j += 4) {
        int i0 = esrc[j], i1 = esrc[j + 1], i2 = esrc[j + 2], i3 = esrc[j + 3];
        float v0 = x[(size_t)i0 * D_IN + lane];
        float v1 = x[(size_t)i1 * D_IN + lane];
        float v2 = x[(size_t)i2 * D_IN + lane];
        float v3 = x[(size_t)i3 * D_IN + lane];
        #pragma unroll
        for (int u = 0; u < 4; u++) {
            float vv = (u == 0) ? v0 : (u == 1) ? v1 : (u == 2) ? v2 : v3;
            float msg = fmaxf(vv, 0.f) + 1e-7f;
            float p = __expf(msg);
            s += p;
            t = fmaf(msg, p, t);
        }
    }
    for (; j < je; j++) {
        int sv = esrc[j];
        float vv = x[(size_t)sv * D_IN + lane];
        float msg = fmaxf(vv, 0.f) + 1e-7f;
        float p = __expf(msg);
        s += p;
        t = fmaf(msg, p, t);
    }
    float agg = t / (s + 1e-16f);    // deg==0 -> 0/(1e-16) = 0
    h[(size_t)node * D_IN + lane] = agg + xn;
}

// ==================== GEMM1 + fused BN stats ====================
__global__ __launch_bounds__(256) void gemm1_kernel(const float* __restrict__ A,
                                                    const float* __restrict__ W,
                                                    const float* __restrict__ bias,
                                                    float* __restrict__ Bout,
                                                    float* __restrict__ S,
                                                    float* __restrict__ Q) {
    __shared__ float sW[64 * 128];  // 32 KB; reused as reduction space in epilogue
    const int tid = threadIdx.x;
    {
        const float4* Wv = (const float4*)W;
        float4* sWv = (float4*)sW;
        #pragma unroll
        for (int i = tid; i < 64 * 128 / 4; i += 256) sWv[i] = Wv[i];
    }
    __syncthreads();
    const int tx = tid & 15;   // 16 col-groups of 8 -> 128 cols
    const int ty = tid >> 4;   // 16 row-groups of 4 -> 64 rows
    const int c0 = tx * 8;
    const int row0 = blockIdx.x * 64 + ty * 4;

    float acc[4][8];
    #pragma unroll
    for (int i = 0; i < 4; i++)
        #pragma unroll
        for (int j = 0; j < 8; j++) acc[i][j] = bias[c0 + j];

    for (int k = 0; k < 64; k += 4) {
        float a[4][4];
        #pragma unroll
        for (int i = 0; i < 4; i++) {
            int r = min(row0 + i, N_NODES - 1);
            float4 t4 = *(const float4*)&A[(size_t)r * 64 + k];
            a[i][0] = t4.x; a[i][1] = t4.y; a[i][2] = t4.z; a[i][3] = t4.w;
        }
        #pragma unroll
        for (int kk = 0; kk < 4; kk++) {
            float4 w0 = *(const float4*)&sW[(k + kk) * 128 + c0];
            float4 w1 = *(const float4*)&sW[(k + kk) * 128 + c0 + 4];
            #pragma unroll
            for (int i = 0; i < 4; i++) {
                float ai = a[i][kk];
                acc[i][0] = fmaf(ai, w0.x, acc[i][0]);
                acc[i][1] = fmaf(ai, w0.y, acc[i][1]);
                acc[i][2] = fmaf(ai, w0.z, acc[i][2]);
                acc[i][3] = fmaf(ai, w0.w, acc[i][3]);
                acc[i][4] = fmaf(ai, w1.x, acc[i][4]);
                acc[i][5] = fmaf(ai, w1.y, acc[i][5]);
                acc[i][6] = fmaf(ai, w1.z, acc[i][6]);
                acc[i][7] = fmaf(ai, w1.w, acc[i][7]);
            }
        }
    }
    #pragma unroll
    for (int i = 0; i < 4; i++) {
        int r = row0 + i;
        if (r < N_NODES) {
            float4 o0 = make_float4(acc[i][0], acc[i][1], acc[i][2], acc[i][3]);
            float4 o1 = make_float4(acc[i][4], acc[i][5], acc[i][6], acc[i][7]);
            *(float4*)&Bout[(size_t)r * 128 + c0]     = o0;
            *(float4*)&Bout[(size_t)r * 128 + c0 + 4] = o1;
        }
    }
    // fused BN stats
    float s8[8], q8[8];
    #pragma unroll
    for (int j = 0; j < 8; j++) { s8[j] = 0.f; q8[j] = 0.f; }
    #pragma unroll
    for (int i = 0; i < 4; i++) {
        if (row0 + i < N_NODES) {
            #pragma unroll
            for (int j = 0; j < 8; j++) {
                float v = acc[i][j];
                s8[j] += v; q8[j] += v * v;
            }
        }
    }
    __syncthreads();
    float* sSum = sW;              // [16][128]
    float* sSq  = sW + 16 * 128;   // [16][128]
    #pragma unroll
    for (int j = 0; j < 8; j++) {
        sSum[ty * 128 + c0 + j] = s8[j];
        sSq[ty * 128 + c0 + j]  = q8[j];
    }
    __syncthreads();
    if (tid < 128) {
        float s = 0.f;
        #pragma unroll
        for (int t = 0; t < 16; t++) s += sSum[t * 128 + tid];
        atomicAdd(&S[tid], s);
    } else {
        int c = tid - 128;
        float q = 0.f;
        #pragma unroll
        for (int t = 0; t < 16; t++) q += sSq[t * 128 + c];
        atomicAdd(&Q[c], q);
    }
}

__global__ void bnfin_kernel(const float* __restrict__ S, const float* __restrict__ Q,
                             const float* __restrict__ gamma, const float* __restrict__ beta,
                             float* __restrict__ ss) {
    int c = threadIdx.x;
    float mean = S[c] * (1.f / N_NODES);
    float var = fmaxf(Q[c] * (1.f / N_NODES) - mean * mean, 0.f);
    float sc = gamma[c] * rsqrtf(var + 1e-5f);
    ss[c] = sc;
    ss[D_HID + c] = beta[c] - mean * sc;
}

// ==================== GEMM2 ====================
__device__ __forceinline__ float mish_f(float v) {
    if (v > 30.f) return v;
    float u = __expf(v);
    float t = (u + 1.f) * (u + 1.f);
    return v * (t - 1.f) / (t + 1.f);  // = v * tanh(softplus(v)), exact identity
}

__global__ __launch_bounds__(256) void gemm2_kernel(const float* __restrict__ H,
                                                    const float* __restrict__ ss,
                                                    const float* __restrict__ W,
                                                    const float* __restrict__ bias,
                                                    float* __restrict__ out, int domish) {
    __shared__ float sW[128 * 64];  // 32 KB
    const int tid = threadIdx.x;
    {
        const float4* Wv = (const float4*)W;
        float4* sWv = (float4*)sW;
        #pragma unroll
        for (int i = tid; i < 128 * 64 / 4; i += 256) sWv[i] = Wv[i];
    }
    __syncthreads();
    const int tx = tid & 7;    // 8 col-groups of 8 -> 64 cols
    const int ty = tid >> 3;   // 32 row-groups of 4 -> 128 rows
    const int c0 = tx * 8;
    const int row0 = blockIdx.x * 128 + ty * 4;

    float acc[4][8];
    #pragma unroll
    for (int i = 0; i < 4; i++)
        #pragma unroll
        for (int j = 0; j < 8; j++) acc[i][j] = bias[c0 + j];

    for (int k = 0; k < 128; k += 4) {
        float4 sc4 = *(const float4*)&ss[k];
        float4 sh4 = *(const float4*)&ss[D_HID + k];
        float a[4][4];
        #pragma unroll
        for (int i = 0; i < 4; i++) {
            int r = min(row0 + i, N_NODES - 1);
            float4 t4 = *(const float4*)&H[(size_t)r * 128 + k];
            a[i][0] = fmaxf(fmaf(t4.x, sc4.x, sh4.x), 0.f);
            a[i][1] = fmaxf(fmaf(t4.y, sc4.y, sh4.y), 0.f);
            a[i][2] = fmaxf(fmaf(t4.z, sc4.z, sh4.z), 0.f);
            a[i][3] = fmaxf(fmaf(t4.w, sc4.w, sh4.w), 0.f);
        }
        #pragma unroll
        for (int kk = 0; kk < 4; kk++) {
            float4 w0 = *(const float4*)&sW[(k + kk) * 64 + c0];
            float4 w1 = *(const float4*)&sW[(k + kk) * 64 + c0 + 4];
            #pragma unroll
            for (int i = 0; i < 4; i++) {
                float ai = a[i][kk];
                acc[i][0] = fmaf(ai, w0.x, acc[i][0]);
                acc[i][1] = fmaf(ai, w0.y, acc[i][1]);
                acc[i][2] = fmaf(ai, w0.z, acc[i][2]);
                acc[i][3] = fmaf(ai, w0.w, acc[i][3]);
                acc[i][4] = fmaf(ai, w1.x, acc[i][4]);
                acc[i][5] = fmaf(ai, w1.y, acc[i][5]);
                acc[i][6] = fmaf(ai, w1.z, acc[i][6]);
                acc[i][7] = fmaf(ai, w1.w, acc[i][7]);
            }
        }
    }
    #pragma unroll
    for (int i = 0; i < 4; i++) {
        int r = row0 + i;
        if (r < N_NODES) {
            float v[8];
            #pragma unroll
            for (int j = 0; j < 8; j++) v[j] = domish ? mish_f(acc[i][j]) : acc[i][j];
            float4 o0 = make_float4(v[0], v[1], v[2], v[3]);
            float4 o1 = make_float4(v[4], v[5], v[6], v[7]);
            *(float4*)&out[(size_t)r * 64 + c0]     = o0;
            *(float4*)&out[(size_t)r * 64 + c0 + 4] = o1;
        }
    }
}

// ============================ launch ============================

extern "C" void kernel_launch(void* const* d_in, const int* in_sizes, int n_in,
                              void* d_out, int out_size, void* d_ws, size_t ws_size,
                              hipStream_t stream) {
    const float* x     = (const float*)d_in[0];
    const int*   ei    = (const int*)d_in[1];
    const float* W1    = (const float*)d_in[2];
    const float* b1    = (const float*)d_in[3];
    const float* gamma = (const float*)d_in[4];
    const float* beta  = (const float*)d_in[5];
    const float* W2    = (const float*)d_in[6];
    const float* b2    = (const float*)d_in[7];
    float* out = (float*)d_out;

    const int* src = ei;
    const int* dst = ei + N_EDGES;

    char* base = (char*)d_ws;
    size_t o = 0;
    auto take = [&](size_t bytes) -> char* {
        char* p = base + o;
        o = (o + bytes + 255) & ~(size_t)255;
        return p;
    };
    int* deg     = (int*)take((size_t)N_NODES * 4);
    int* cursor  = (int*)take((size_t)N_NODES * 4);
    int* off     = (int*)take((size_t)(N_NODES + 1) * 4);
    int* esrc    = (int*)take((size_t)N_EDGES * 4);
    int* bsum    = (int*)take((size_t)N_SB * 4);
    int* boff    = (int*)take((size_t)N_SB * 4);
    float* bn    = (float*)take(512 * 4);  // S[128] Q[128] scale/shift[256]
    float* xbuf  = (float*)take((size_t)N_NODES * D_IN * 4);
    float* hbuf  = (float*)take((size_t)N_NODES * D_IN * 4);
    float* h1buf = (float*)take((size_t)N_NODES * D_HID * 4);

    // CSR build (once per call; dst is layer-invariant)
    hipMemsetAsync(deg, 0, (size_t)N_NODES * 4, stream);
    hipMemsetAsync(cursor, 0, (size_t)N_NODES * 4, stream);
    count_kernel<<<(N_EDGES + 255) / 256, 256, 0, stream>>>(dst, deg, N_EDGES);
    scan_reduce_kernel<<<N_SB, SCAN_B, 0, stream>>>(deg, bsum);
    scan_sums_kernel<<<1, SCAN_B, 0, stream>>>(bsum, boff);
    scan_write_kernel<<<N_SB, SCAN_B, 0, stream>>>(deg, boff, off);
    scatter_kernel<<<(N_EDGES + 255) / 256, 256, 0, stream>>>(src, dst, off, cursor, esrc, N_EDGES);

    for (int L = 0; L < 4; L++) {
        const float* cx = (L == 0) ? x : xbuf;
        agg_kernel<<<N_NODES / 4, 256, 0, stream>>>(cx, off, esrc, hbuf);
        hipMemsetAsync(bn, 0, 256 * 4, stream);  // zero S/Q before gemm1's fused stats
        gemm1_kernel<<<(N_NODES + 63) / 64, 256, 0, stream>>>(
            hbuf, W1 + (size_t)L * D_IN * D_HID, b1 + (size_t)L * D_HID, h1buf,
            bn, bn + 128);
        bnfin_kernel<<<1, 128, 0, stream>>>(bn, bn + 128, gamma + (size_t)L * D_HID,
                                            beta + (size_t)L * D_HID, bn + 256);
        gemm2_kernel<<<(N_NODES + 127) / 128, 256, 0, stream>>>(
            h1buf, bn + 256, W2 + (size_t)L * D_HID * D_IN, b2 + (size_t)L * D_IN,
            (L < 3) ? xbuf : out, (L < 3) ? 1 : 0);
    }
}

// Round 5
// 517.852 us; speedup vs baseline: 2.1860x; 1.0312x over previous
//
#include <hip/hip_runtime.h>
#include <math.h>

#define N_NODES 50000
#define N_EDGES 800000
#define D_IN 64
#define D_HID 128
#define SCAN_B 256
#define N_SB ((N_NODES + SCAN_B - 1) / SCAN_B)  // 196
#define NPB 256                                  // nodes per bucket
#define NB ((N_NODES + NPB - 1) / NPB)           // 196 buckets
#define P1_BLOCKS 256
#define EPB (N_EDGES / P1_BLOCKS)                // 3125 edges per pass-1 block

// ============================ CSR build ============================

__global__ void count_kernel(const int* __restrict__ dst, int* __restrict__ deg, int E) {
    int i = blockIdx.x * blockDim.x + threadIdx.x;
    if (i < E) atomicAdd(&deg[dst[i]], 1);
}

// Phase A: per-block sums of deg (coalesced)
__global__ __launch_bounds__(SCAN_B) void scan_reduce_kernel(const int* __restrict__ deg,
                                                             int* __restrict__ bsum) {
    __shared__ int s[SCAN_B];
    int i = blockIdx.x * SCAN_B + threadIdx.x;
    int v = (i < N_NODES) ? deg[i] : 0;
    s[threadIdx.x] = v;
    __syncthreads();
    #pragma unroll
    for (int o = SCAN_B / 2; o > 0; o >>= 1) {
        if (threadIdx.x < o) s[threadIdx.x] += s[threadIdx.x + o];
        __syncthreads();
    }
    if (threadIdx.x == 0) bsum[blockIdx.x] = s[0];
}

// Phase B: single small block — exclusive scan of the 196 block sums
__global__ __launch_bounds__(SCAN_B) void scan_sums_kernel(const int* __restrict__ bsum,
                                                           int* __restrict__ boff) {
    __shared__ int s[SCAN_B];
    int t = threadIdx.x;
    int v = (t < N_SB) ? bsum[t] : 0;
    s[t] = v;
    __syncthreads();
    #pragma unroll
    for (int o = 1; o < SCAN_B; o <<= 1) {
        int u = (t >= o) ? s[t - o] : 0;
        __syncthreads();
        s[t] += u;
        __syncthreads();
    }
    if (t < N_SB) boff[t] = s[t] - v;  // exclusive
}

// Phase C: per-block scan + block offset -> off[i]; last element writes off[n]
__global__ __launch_bounds__(SCAN_B) void scan_write_kernel(const int* __restrict__ deg,
                                                            const int* __restrict__ boff,
                                                            int* __restrict__ off) {
    __shared__ int s[SCAN_B];
    int t = threadIdx.x;
    int i = blockIdx.x * SCAN_B + t;
    int v = (i < N_NODES) ? deg[i] : 0;
    s[t] = v;
    __syncthreads();
    #pragma unroll
    for (int o = 1; o < SCAN_B; o <<= 1) {
        int u = (t >= o) ? s[t - o] : 0;
        __syncthreads();
        s[t] += u;
        __syncthreads();
    }
    int incl = s[t] + boff[blockIdx.x];
    if (i < N_NODES) off[i] = incl - v;
    if (i == N_NODES - 1) off[N_NODES] = incl;
}

// ==================== binned scatter (2-pass, write-amp fix) ====================
// gcur[b] = off[b*NPB]: running allocation cursor for bucket b's ebuf region.
__global__ void bin_init_kernel(const int* __restrict__ off, int* __restrict__ gcur) {
    int b = threadIdx.x;
    if (b < NB) gcur[b] = off[min(b * NPB, N_NODES)];
}

// Pass 1: block-local histogram -> reserve per-bucket ranges -> append (src,dst)
// pairs. Writes are sequential per (block,bucket) stream (full-line fills).
__global__ __launch_bounds__(256) void bin_pass1_kernel(const int* __restrict__ src,
                                                        const int* __restrict__ dst,
                                                        int* __restrict__ gcur,
                                                        int2* __restrict__ ebuf) {
    __shared__ int hist[NB];
    __shared__ int base[NB];
    const int tid = threadIdx.x;
    const int e0 = blockIdx.x * EPB, e1 = e0 + EPB;
    for (int b = tid; b < NB; b += 256) hist[b] = 0;
    __syncthreads();
    for (int i = e0 + tid; i < e1; i += 256)
        atomicAdd(&hist[dst[i] >> 8], 1);
    __syncthreads();
    for (int b = tid; b < NB; b += 256) {
        base[b] = atomicAdd(&gcur[b], hist[b]);
        hist[b] = 0;  // reuse as block-local cursor
    }
    __syncthreads();
    for (int i = e0 + tid; i < e1; i += 256) {
        int d = dst[i];
        int b = d >> 8;
        int slot = base[b] + atomicAdd(&hist[b], 1);
        ebuf[slot] = make_int2(src[i], d);
    }
}

// Pass 2: one block per bucket; place each pair at off[dst]+cursor. All the
// random traffic (off window, esrc window ~16KB) is L2/L1-resident.
__global__ __launch_bounds__(256) void bin_pass2_kernel(const int* __restrict__ off,
                                                        const int2* __restrict__ ebuf,
                                                        int* __restrict__ esrc) {
    __shared__ int soff[NPB];
    __shared__ int cur[NPB];
    const int b = blockIdx.x;
    const int tid = threadIdx.x;
    const int n0 = b * NPB;
    soff[tid] = off[min(n0 + tid, N_NODES)];
    cur[tid] = 0;
    __syncthreads();
    const int e0 = soff[0];
    const int e1 = off[min(n0 + NPB, N_NODES)];
    for (int i = e0 + tid; i < e1; i += 256) {
        int2 p = ebuf[i];
        int dl = p.y - n0;
        int slot = soff[dl] + atomicAdd(&cur[dl], 1);
        esrc[slot] = p.x;
    }
}

// ==================== softmax aggregation + residual ====================
// One wave per node, lane = channel. No-max softmax (values O(1), fp32-safe;
// identical math to max-subtracted form). 8-edge unroll -> 8 outstanding
// row-gathers per wave (latency-bound fix).
__global__ __launch_bounds__(256) void agg_kernel(const float* __restrict__ x,
                                                  const int* __restrict__ off,
                                                  const int* __restrict__ esrc,
                                                  float* __restrict__ h) {
    int node = blockIdx.x * 4 + (threadIdx.x >> 6);
    int lane = threadIdx.x & 63;
    if (node >= N_NODES) return;
    float xn = x[(size_t)node * D_IN + lane];  // residual, load early
    int jb = off[node], je = off[node + 1];
    float s = 0.f, t = 0.f;
    int j = jb;
    for (; j + 8 <= je; j += 8) {
        int idx[8];
        #pragma unroll
        for (int u = 0; u < 8; u++) idx[u] = esrc[j + u];
        float v[8];
        #pragma unroll
        for (int u = 0; u < 8; u++) v[u] = x[(size_t)idx[u] * D_IN + lane];
        #pragma unroll
        for (int u = 0; u < 8; u++) {
            float msg = fmaxf(v[u], 0.f) + 1e-7f;
            float p = __expf(msg);
            s += p;
            t = fmaf(msg, p, t);
        }
    }
    for (; j + 4 <= je; j += 4) {
        int i0 = esrc[j], i1 = esrc[j + 1], i2 = esrc[j + 2], i3 = esrc[j + 3];
        float v0 = x[(size_t)i0 * D_IN + lane];
        float v1 = x[(size_t)i1 * D_IN + lane];
        float v2 = x[(size_t)i2 * D_IN + lane];
        float v3 = x[(size_t)i3 * D_IN + lane];
        #pragma unroll
        for (int u = 0; u < 4; u++) {
            float vv = (u == 0) ? v0 : (u == 1) ? v1 : (u == 2) ? v2 : v3;
            float msg = fmaxf(vv, 0.f) + 1e-7f;
            float p = __expf(msg);
            s += p;
            t = fmaf(msg, p, t);
        }
    }
    for (; j < je; j++) {
        int sv = esrc[j];
        float vv = x[(size_t)sv * D_IN + lane];
        float msg = fmaxf(vv, 0.f) + 1e-7f;
        float p = __expf(msg);
        s += p;
        t = fmaf(msg, p, t);
    }
    float agg = t / (s + 1e-16f);    // deg==0 -> 0/(1e-16) = 0
    h[(size_t)node * D_IN + lane] = agg + xn;
}

// ==================== GEMM1 + fused BN stats ====================
__global__ __launch_bounds__(256) void gemm1_kernel(const float* __restrict__ A,
                                                    const float* __restrict__ W,
                                                    const float* __restrict__ bias,
                                                    float* __restrict__ Bout,
                                                    float* __restrict__ S,
                                                    float* __restrict__ Q) {
    __shared__ float sW[64 * 128];  // 32 KB; reused as reduction space in epilogue
    const int tid = threadIdx.x;
    {
        const float4* Wv = (const float4*)W;
        float4* sWv = (float4*)sW;
        #pragma unroll
        for (int i = tid; i < 64 * 128 / 4; i += 256) sWv[i] = Wv[i];
    }
    __syncthreads();
    const int tx = tid & 15;   // 16 col-groups of 8 -> 128 cols
    const int ty = tid >> 4;   // 16 row-groups of 4 -> 64 rows
    const int c0 = tx * 8;
    const int row0 = blockIdx.x * 64 + ty * 4;

    float acc[4][8];
    #pragma unroll
    for (int i = 0; i < 4; i++)
        #pragma unroll
        for (int j = 0; j < 8; j++) acc[i][j] = bias[c0 + j];

    for (int k = 0; k < 64; k += 4) {
        float a[4][4];
        #pragma unroll
        for (int i = 0; i < 4; i++) {
            int r = min(row0 + i, N_NODES - 1);
            float4 t4 = *(const float4*)&A[(size_t)r * 64 + k];
            a[i][0] = t4.x; a[i][1] = t4.y; a[i][2] = t4.z; a[i][3] = t4.w;
        }
        #pragma unroll
        for (int kk = 0; kk < 4; kk++) {
            float4 w0 = *(const float4*)&sW[(k + kk) * 128 + c0];
            float4 w1 = *(const float4*)&sW[(k + kk) * 128 + c0 + 4];
            #pragma unroll
            for (int i = 0; i < 4; i++) {
                float ai = a[i][kk];
                acc[i][0] = fmaf(ai, w0.x, acc[i][0]);
                acc[i][1] = fmaf(ai, w0.y, acc[i][1]);
                acc[i][2] = fmaf(ai, w0.z, acc[i][2]);
                acc[i][3] = fmaf(ai, w0.w, acc[i][3]);
                acc[i][4] = fmaf(ai, w1.x, acc[i][4]);
                acc[i][5] = fmaf(ai, w1.y, acc[i][5]);
                acc[i][6] = fmaf(ai, w1.z, acc[i][6]);
                acc[i][7] = fmaf(ai, w1.w, acc[i][7]);
            }
        }
    }
    #pragma unroll
    for (int i = 0; i < 4; i++) {
        int r = row0 + i;
        if (r < N_NODES) {
            float4 o0 = make_float4(acc[i][0], acc[i][1], acc[i][2], acc[i][3]);
            float4 o1 = make_float4(acc[i][4], acc[i][5], acc[i][6], acc[i][7]);
            *(float4*)&Bout[(size_t)r * 128 + c0]     = o0;
            *(float4*)&Bout[(size_t)r * 128 + c0 + 4] = o1;
        }
    }
    // fused BN stats
    float s8[8], q8[8];
    #pragma unroll
    for (int j = 0; j < 8; j++) { s8[j] = 0.f; q8[j] = 0.f; }
    #pragma unroll
    for (int i = 0; i < 4; i++) {
        if (row0 + i < N_NODES) {
            #pragma unroll
            for (int j = 0; j < 8; j++) {
                float v = acc[i][j];
                s8[j] += v; q8[j] += v * v;
            }
        }
    }
    __syncthreads();
    float* sSum = sW;              // [16][128]
    float* sSq  = sW + 16 * 128;   // [16][128]
    #pragma unroll
    for (int j = 0; j < 8; j++) {
        sSum[ty * 128 + c0 + j] = s8[j];
        sSq[ty * 128 + c0 + j]  = q8[j];
    }
    __syncthreads();
    if (tid < 128) {
        float s = 0.f;
        #pragma unroll
        for (int t = 0; t < 16; t++) s += sSum[t * 128 + tid];
        atomicAdd(&S[tid], s);
    } else {
        int c = tid - 128;
        float q = 0.f;
        #pragma unroll
        for (int t = 0; t < 16; t++) q += sSq[t * 128 + c];
        atomicAdd(&Q[c], q);
    }
}

__global__ void bnfin_kernel(const float* __restrict__ S, const float* __restrict__ Q,
                             const float* __restrict__ gamma, const float* __restrict__ beta,
                             float* __restrict__ ss) {
    int c = threadIdx.x;
    float mean = S[c] * (1.f / N_NODES);
    float var = fmaxf(Q[c] * (1.f / N_NODES) - mean * mean, 0.f);
    float sc = gamma[c] * rsqrtf(var + 1e-5f);
    ss[c] = sc;
    ss[D_HID + c] = beta[c] - mean * sc;
}

// ==================== GEMM2 ====================
__device__ __forceinline__ float mish_f(float v) {
    if (v > 30.f) return v;
    float u = __expf(v);
    float t = (u + 1.f) * (u + 1.f);
    return v * (t - 1.f) / (t + 1.f);  // = v * tanh(softplus(v)), exact identity
}

__global__ __launch_bounds__(256) void gemm2_kernel(const float* __restrict__ H,
                                                    const float* __restrict__ ss,
                                                    const float* __restrict__ W,
                                                    const float* __restrict__ bias,
                                                    float* __restrict__ out, int domish) {
    __shared__ float sW[128 * 64];  // 32 KB
    const int tid = threadIdx.x;
    {
        const float4* Wv = (const float4*)W;
        float4* sWv = (float4*)sW;
        #pragma unroll
        for (int i = tid; i < 128 * 64 / 4; i += 256) sWv[i] = Wv[i];
    }
    __syncthreads();
    const int tx = tid & 7;    // 8 col-groups of 8 -> 64 cols
    const int ty = tid >> 3;   // 32 row-groups of 4 -> 128 rows
    const int c0 = tx * 8;
    const int row0 = blockIdx.x * 128 + ty * 4;

    float acc[4][8];
    #pragma unroll
    for (int i = 0; i < 4; i++)
        #pragma unroll
        for (int j = 0; j < 8; j++) acc[i][j] = bias[c0 + j];

    for (int k = 0; k < 128; k += 4) {
        float4 sc4 = *(const float4*)&ss[k];
        float4 sh4 = *(const float4*)&ss[D_HID + k];
        float a[4][4];
        #pragma unroll
        for (int i = 0; i < 4; i++) {
            int r = min(row0 + i, N_NODES - 1);
            float4 t4 = *(const float4*)&H[(size_t)r * 128 + k];
            a[i][0] = fmaxf(fmaf(t4.x, sc4.x, sh4.x), 0.f);
            a[i][1] = fmaxf(fmaf(t4.y, sc4.y, sh4.y), 0.f);
            a[i][2] = fmaxf(fmaf(t4.z, sc4.z, sh4.z), 0.f);
            a[i][3] = fmaxf(fmaf(t4.w, sc4.w, sh4.w), 0.f);
        }
        #pragma unroll
        for (int kk = 0; kk < 4; kk++) {
            float4 w0 = *(const float4*)&sW[(k + kk) * 64 + c0];
            float4 w1 = *(const float4*)&sW[(k + kk) * 64 + c0 + 4];
            #pragma unroll
            for (int i = 0; i < 4; i++) {
                float ai = a[i][kk];
                acc[i][0] = fmaf(ai, w0.x, acc[i][0]);
                acc[i][1] = fmaf(ai, w0.y, acc[i][1]);
                acc[i][2] = fmaf(ai, w0.z, acc[i][2]);
                acc[i][3] = fmaf(ai, w0.w, acc[i][3]);
                acc[i][4] = fmaf(ai, w1.x, acc[i][4]);
                acc[i][5] = fmaf(ai, w1.y, acc[i][5]);
                acc[i][6] = fmaf(ai, w1.z, acc[i][6]);
                acc[i][7] = fmaf(ai, w1.w, acc[i][7]);
            }
        }
    }
    #pragma unroll
    for (int i = 0; i < 4; i++) {
        int r = row0 + i;
        if (r < N_NODES) {
            float v[8];
            #pragma unroll
            for (int j = 0; j < 8; j++) v[j] = domish ? mish_f(acc[i][j]) : acc[i][j];
            float4 o0 = make_float4(v[0], v[1], v[2], v[3]);
            float4 o1 = make_float4(v[4], v[5], v[6], v[7]);
            *(float4*)&out[(size_t)r * 64 + c0]     = o0;
            *(float4*)&out[(size_t)r * 64 + c0 + 4] = o1;
        }
    }
}

// ============================ launch ============================

extern "C" void kernel_launch(void* const* d_in, const int* in_sizes, int n_in,
                              void* d_out, int out_size, void* d_ws, size_t ws_size,
                              hipStream_t stream) {
    const float* x     = (const float*)d_in[0];
    const int*   ei    = (const int*)d_in[1];
    const float* W1    = (const float*)d_in[2];
    const float* b1    = (const float*)d_in[3];
    const float* gamma = (const float*)d_in[4];
    const float* beta  = (const float*)d_in[5];
    const float* W2    = (const float*)d_in[6];
    const float* b2    = (const float*)d_in[7];
    float* out = (float*)d_out;

    const int* src = ei;
    const int* dst = ei + N_EDGES;

    char* base = (char*)d_ws;
    size_t o = 0;
    auto take = [&](size_t bytes) -> char* {
        char* p = base + o;
        o = (o + bytes + 255) & ~(size_t)255;
        return p;
    };
    int* deg     = (int*)take((size_t)N_NODES * 4);
    int* off     = (int*)take((size_t)(N_NODES + 1) * 4);
    int* esrc    = (int*)take((size_t)N_EDGES * 4);
    int2* ebuf   = (int2*)take((size_t)N_EDGES * 8);
    int* bsum    = (int*)take((size_t)N_SB * 4);
    int* boff    = (int*)take((size_t)N_SB * 4);
    int* gcur    = (int*)take((size_t)NB * 4);
    float* bn    = (float*)take(512 * 4);  // S[128] Q[128] scale/shift[256]
    float* xbuf  = (float*)take((size_t)N_NODES * D_IN * 4);
    float* hbuf  = (float*)take((size_t)N_NODES * D_IN * 4);
    float* h1buf = (float*)take((size_t)N_NODES * D_HID * 4);

    // CSR build (once per call; dst is layer-invariant)
    hipMemsetAsync(deg, 0, (size_t)N_NODES * 4, stream);
    count_kernel<<<(N_EDGES + 255) / 256, 256, 0, stream>>>(dst, deg, N_EDGES);
    scan_reduce_kernel<<<N_SB, SCAN_B, 0, stream>>>(deg, bsum);
    scan_sums_kernel<<<1, SCAN_B, 0, stream>>>(bsum, boff);
    scan_write_kernel<<<N_SB, SCAN_B, 0, stream>>>(deg, boff, off);
    bin_init_kernel<<<1, 256, 0, stream>>>(off, gcur);
    bin_pass1_kernel<<<P1_BLOCKS, 256, 0, stream>>>(src, dst, gcur, ebuf);
    bin_pass2_kernel<<<NB, 256, 0, stream>>>(off, ebuf, esrc);

    for (int L = 0; L < 4; L++) {
        const float* cx = (L == 0) ? x : xbuf;
        agg_kernel<<<N_NODES / 4, 256, 0, stream>>>(cx, off, esrc, hbuf);
        hipMemsetAsync(bn, 0, 256 * 4, stream);  // zero S/Q before gemm1's fused stats
        gemm1_kernel<<<(N_NODES + 63) / 64, 256, 0, stream>>>(
            hbuf, W1 + (size_t)L * D_IN * D_HID, b1 + (size_t)L * D_HID, h1buf,
            bn, bn + 128);
        bnfin_kernel<<<1, 128, 0, stream>>>(bn, bn + 128, gamma + (size_t)L * D_HID,
                                            beta + (size_t)L * D_HID, bn + 256);
        gemm2_kernel<<<(N_NODES + 127) / 128, 256, 0, stream>>>(
            h1buf, bn + 256, W2 + (size_t)L * D_HID * D_IN, b2 + (size_t)L * D_IN,
            (L < 3) ? xbuf : out, (L < 3) ? 1 : 0);
    }
}